// Round 5
// baseline (102.350 us; speedup 1.0000x reference)
//
#include <hip/hip_runtime.h>
#include <hip/hip_bf16.h>

// Problem constants
#define BATCH 4096
#define FIELD 20000
#define EMBED 64
#define KC     25           // 800-int chunks per row
#define KSPAN  800          // ints per chunk (FIELD/KC)
#define SPW    25           // MFMA k-steps per chunk (KSPAN/32)
#define MTILES 256          // BATCH/16
#define MSTRIDE 28          // u32 words per chunk record (25 used + 3 pad, 112 B, 16B-aligned)
#define CHUNKS (BATCH * KC) // 102400
#define WSWZ_BYTES (FIELD * EMBED * 2)   // 2,560,000 B (16B-aligned)

typedef __attribute__((ext_vector_type(4))) float  f32x4;
typedef __attribute__((ext_vector_type(8))) short  short8;   // 8 bf16 MFMA frag
typedef __attribute__((ext_vector_type(4))) unsigned int u32x4;
typedef unsigned long long u64;

__device__ __forceinline__ unsigned bf16_rtne(float f) {
    unsigned u = __builtin_bit_cast(unsigned, f);
    return (u + 0x7FFFu + ((u >> 16) & 1u)) >> 16;   // round-to-nearest-even
}

// Pre-swizzle W -> bf16 MFMA-B-fragment order (verified R2-R4) + zero d_out
// (atomic epilogue accumulates; harness doesn't re-zero between replays).
__global__ __launch_bounds__(256) void prep_w_kernel(const float* __restrict__ W,
                                                     unsigned int* __restrict__ Wswz,
                                                     float* __restrict__ out) {
    if (blockIdx.x < 512) {            // zero 1 MB output
        float2 z; z.x = 0.f; z.y = 0.f;
        ((float2*)out)[blockIdx.x * 256 + threadIdx.x] = z;
    }

    __shared__ float lds[32 * 65];               // [32 k][64 col] padded +1
    const int t  = threadIdx.x;
    const int s0 = blockIdx.x;                   // 32-k chunk

    const float4* src = (const float4*)(W + (size_t)s0 * 2048);
    float4 a = src[t * 2 + 0];
    float4 b = src[t * 2 + 1];
    int l  = t * 8;
    int kl = l >> 6, c = l & 63;
    float* dst = lds + kl * 65 + c;
    dst[0] = a.x; dst[1] = a.y; dst[2] = a.z; dst[3] = a.w;
    dst[4] = b.x; dst[5] = b.y; dst[6] = b.z; dst[7] = b.w;
    __syncthreads();

    const int lane = t & 63, tq = t >> 6;
    const int khi = lane >> 4, lrow = lane & 15;
    const int col = tq * 16 + lrow;
    u32x4 o;
#pragma unroll
    for (int j2 = 0; j2 < 4; ++j2) {
        int kloc = khi * 8 + 2 * j2;
        float w0 = lds[kloc * 65 + col];
        float w1 = lds[(kloc + 1) * 65 + col];
        o[j2] = bf16_rtne(w0) | (bf16_rtne(w1) << 16);
    }
    *(u32x4*)(Wswz + ((size_t)(s0 * 4 + tq) * 64 + lane) * 4) = o;
}

// Pure streaming compress: one wave per (row, kc) chunk. 12 full + 1 half
// coalesced 256 B loads -> 13 ballots -> lane0 stores 7 dwordx4 mask words.
// No LDS, no inter-row serialization; structurally a fill-rate kernel.
// Mask word s (0..24) bit t = (indices[row][kc*800 + 32s + t] != 0).
__global__ __launch_bounds__(256) void compress_kernel(const int* __restrict__ idxm,
                                                       unsigned* __restrict__ gm) {
    const int lane = threadIdx.x & 63;
    const int w    = blockIdx.x * 4 + (threadIdx.x >> 6);
    const int row  = w / KC;
    const int kc   = w % KC;
    const int* rp  = idxm + (size_t)row * FIELD + kc * KSPAN;

    int v[12];
#pragma unroll
    for (int c = 0; c < 12; ++c) v[c] = rp[c * 64 + lane];
    int vt = 0;
    if (lane < 32) vt = rp[768 + lane];

    unsigned wd[25];
#pragma unroll
    for (int c = 0; c < 12; ++c) {
        u64 b = __ballot(v[c] != 0);             // bit l = (int 64c+l) != 0
        wd[2 * c]     = (unsigned)b;
        wd[2 * c + 1] = (unsigned)(b >> 32);
    }
    wd[24] = (unsigned)__ballot(vt != 0);        // lanes>=32 contribute 0

    if (lane == 0) {
        u32x4* dst = (u32x4*)(gm + (size_t)w * MSTRIDE);
#pragma unroll
        for (int i = 0; i < 6; ++i) {
            u32x4 o = {wd[4 * i], wd[4 * i + 1], wd[4 * i + 2], wd[4 * i + 3]};
            dst[i] = o;
        }
        u32x4 o6 = {wd[24], 0u, 0u, 0u};
        dst[6] = o6;
    }
}

// Expand + MFMA: wave (mtile, kc) reads its 16 rows' mask words (L3-resident,
// 7 dwordx4 per lane-row), expands in-register to bf16 {0,1} A-frags (fully
// unrolled -> static indexing, no scratch), MFMA vs L1-resident B, atomicAdd.
__global__ __launch_bounds__(256) void emb_mfma_kernel(const unsigned* __restrict__ gm,
                                                       const unsigned* __restrict__ Wswz,
                                                       float* __restrict__ out) {
    const int lane  = threadIdx.x & 63;
    const int w     = blockIdx.x * 4 + (threadIdx.x >> 6);
    const int mtile = w % MTILES;                // block: same kc, 4 consecutive mtiles
    const int kc    = w / MTILES;
    const int lrow  = lane & 15;
    const int khi   = lane >> 4;                 // 0..3
    const int row   = mtile * 16 + lrow;

    // Load this row-chunk's 25 mask words into registers (static scatter).
    const u32x4* mp = (const u32x4*)(gm + ((size_t)row * KC + kc) * MSTRIDE);
    unsigned M[25];
    {
        u32x4 t0 = mp[0], t1 = mp[1], t2 = mp[2], t3 = mp[3], t4 = mp[4], t5 = mp[5], t6 = mp[6];
        M[0]=t0.x;  M[1]=t0.y;  M[2]=t0.z;  M[3]=t0.w;
        M[4]=t1.x;  M[5]=t1.y;  M[6]=t1.z;  M[7]=t1.w;
        M[8]=t2.x;  M[9]=t2.y;  M[10]=t2.z; M[11]=t2.w;
        M[12]=t3.x; M[13]=t3.y; M[14]=t3.z; M[15]=t3.w;
        M[16]=t4.x; M[17]=t4.y; M[18]=t4.z; M[19]=t4.w;
        M[20]=t5.x; M[21]=t5.y; M[22]=t5.z; M[23]=t5.w;
        M[24]=t6.x;
    }

    const short8* pB = (const short8*)Wswz + (size_t)kc * SPW * 4 * 64 + lane;

    f32x4 acc0 = {0.f, 0.f, 0.f, 0.f};
    f32x4 acc1 = acc0, acc2 = acc0, acc3 = acc0;

#pragma unroll
    for (int s = 0; s < SPW; ++s) {
        unsigned Mw = M[s];                      // static after full unroll
        short8 b0 = pB[0], b1 = pB[64], b2 = pB[128], b3 = pB[192];
        pB += 256;

        unsigned mb = Mw >> (khi * 8);           // this lane's 8 k-bits
        u32x4 av;
#pragma unroll
        for (int j = 0; j < 4; ++j)
            av[j] = (((mb >> (2 * j)) & 1u) ? 0x3F80u : 0u)
                  | (((mb >> (2 * j + 1)) & 1u) ? 0x3F800000u : 0u);
        short8 afrag = __builtin_bit_cast(short8, av);

        acc0 = __builtin_amdgcn_mfma_f32_16x16x32_bf16(afrag, b0, acc0, 0, 0, 0);
        acc1 = __builtin_amdgcn_mfma_f32_16x16x32_bf16(afrag, b1, acc1, 0, 0, 0);
        acc2 = __builtin_amdgcn_mfma_f32_16x16x32_bf16(afrag, b2, acc2, 0, 0, 0);
        acc3 = __builtin_amdgcn_mfma_f32_16x16x32_bf16(afrag, b3, acc3, 0, 0, 0);
    }

    // Epilogue: atomic accumulate (D: col=lane&15, row=khi*4+i) — verified R4.
    float* obase = out + (size_t)mtile * 16 * EMBED;
#pragma unroll
    for (int i = 0; i < 4; ++i) {
        int orow = khi * 4 + i;
        atomicAdd(obase + (size_t)orow * EMBED +      lrow, acc0[i]);
        atomicAdd(obase + (size_t)orow * EMBED + 16 + lrow, acc1[i]);
        atomicAdd(obase + (size_t)orow * EMBED + 32 + lrow, acc2[i]);
        atomicAdd(obase + (size_t)orow * EMBED + 48 + lrow, acc3[i]);
    }
}

extern "C" void kernel_launch(void* const* d_in, const int* in_sizes, int n_in,
                              void* d_out, int out_size, void* d_ws, size_t ws_size,
                              hipStream_t stream) {
    const int*   idxm = (const int*)d_in[0];     // [4096][20000] int32
    const float* W    = (const float*)d_in[1];   // [20000][64] f32
    float*       out  = (float*)d_out;           // [4096][64] f32

    unsigned int* Wswz = (unsigned int*)d_ws;                       // 2.56 MB
    unsigned*     gm   = (unsigned*)((char*)d_ws + WSWZ_BYTES);     // 11.5 MB masks

    hipLaunchKernelGGL(prep_w_kernel, dim3(FIELD / 32), dim3(256), 0, stream,
                       W, Wswz, out);
    hipLaunchKernelGGL(compress_kernel, dim3(CHUNKS / 4), dim3(256), 0, stream,
                       idxm, gm);
    hipLaunchKernelGGL(emb_mfma_kernel, dim3(MTILES * KC / 4), dim3(256), 0, stream,
                       gm, Wswz, out);
}

// Round 6
// 90.758 us; speedup vs baseline: 1.1277x; 1.1277x over previous
//
#include <hip/hip_runtime.h>
#include <hip/hip_bf16.h>

// Problem constants
#define BATCH 4096
#define FIELD 20000
#define EMBED 64
#define KC     25           // 800-int chunks per row
#define KSPAN  800          // ints per chunk (FIELD/KC)
#define SPW    25           // MFMA k-steps per chunk (KSPAN/32)
#define MTILES 256          // BATCH/16
#define LROW_STRIDE 28      // LDS words per row (25 used + 3 pad; 112 B, 16B-aligned)
#define WAVE_LDS (16 * LROW_STRIDE)   // 448 words per wave

typedef __attribute__((ext_vector_type(4))) float  f32x4;
typedef __attribute__((ext_vector_type(8))) short  short8;   // 8 bf16 MFMA frag
typedef __attribute__((ext_vector_type(4))) int    i32x4;
typedef __attribute__((ext_vector_type(4))) unsigned int u32x4;
typedef unsigned long long u64;

__device__ __forceinline__ unsigned bf16_rtne(float f) {
    unsigned u = __builtin_bit_cast(unsigned, f);
    return (u + 0x7FFFu + ((u >> 16) & 1u)) >> 16;   // round-to-nearest-even
}

// Pre-swizzle W -> bf16 MFMA-B-fragment order (verified R2-R5) + zero d_out
// (atomic epilogue accumulates; harness doesn't re-zero between replays).
// B-side k-mapping is LINEAR (k = 32*S + kloc); the ballot-native A-mask
// permutation is inverted on the expand side instead.
__global__ __launch_bounds__(256) void prep_w_kernel(const float* __restrict__ W,
                                                     unsigned int* __restrict__ Wswz,
                                                     float* __restrict__ out) {
    if (blockIdx.x < 512) {            // zero 1 MB output
        float2 z; z.x = 0.f; z.y = 0.f;
        ((float2*)out)[blockIdx.x * 256 + threadIdx.x] = z;
    }

    __shared__ float lds[32 * 65];               // [32 k][64 col] padded +1
    const int t  = threadIdx.x;
    const int s0 = blockIdx.x;                   // 32-k chunk (global step S)

    const float4* src = (const float4*)(W + (size_t)s0 * 2048);
    float4 a = src[t * 2 + 0];
    float4 b = src[t * 2 + 1];
    int l  = t * 8;
    int kl = l >> 6, c = l & 63;
    float* dst = lds + kl * 65 + c;
    dst[0] = a.x; dst[1] = a.y; dst[2] = a.z; dst[3] = a.w;
    dst[4] = b.x; dst[5] = b.y; dst[6] = b.z; dst[7] = b.w;
    __syncthreads();

    const int lane = t & 63, tq = t >> 6;
    const int khi = lane >> 4, lrow = lane & 15;
    const int col = tq * 16 + lrow;
    u32x4 o;
#pragma unroll
    for (int j2 = 0; j2 < 4; ++j2) {
        int kloc = khi * 8 + 2 * j2;
        float w0 = lds[kloc * 65 + col];
        float w1 = lds[(kloc + 1) * 65 + col];
        o[j2] = bf16_rtne(w0) | (bf16_rtne(w1) << 16);
    }
    *(u32x4*)(Wswz + ((size_t)(s0 * 4 + tq) * 64 + lane) * 4) = o;
}

// Fused main kernel (R4 structure, R6 load path). Per wave (mtile, kc):
//  Phase 1: 16 rows x 800 ints via 3x dwordx4 NONTEMPORAL loads + 1 tail dword
//    (4 load instrs/row vs 13). Ballot-native mask words: word 8L+2c+h,
//    bit t = (int 256L+128h+4t+c != 0). Lane0 stores 25 words/row to
//    wave-private LDS. No inter-wave barrier (waves fully independent).
//  Phase 2: per 4 k-steps read 4 mask words; extract bit-pairs to build the
//    bf16 {0,1} A-frag (inverse of ballot permutation; B stays linear).
//  Epilogue: atomicAdd 16x64 tile (verified free, R1/R4).
__global__ __launch_bounds__(256) void emb_mfma_kernel(const int* __restrict__ idxm,
                                                       const unsigned* __restrict__ Wswz,
                                                       float* __restrict__ out) {
    __shared__ unsigned lmask[4 * WAVE_LDS];
    const int lane  = threadIdx.x & 63;
    const int widx  = threadIdx.x >> 6;
    const int w     = blockIdx.x * 4 + widx;
    const int mtile = w % MTILES;
    const int kc    = w / MTILES;
    const int lrow  = lane & 15;
    const int khi   = lane >> 4;                 // 0..3
    unsigned* lm = lmask + widx * WAVE_LDS;

    // ---- Phase 1: compress (ballot-native layout) ----
#pragma unroll 2
    for (int r = 0; r < 16; ++r) {
        const int* rp = idxm + (size_t)(mtile * 16 + r) * FIELD + kc * KSPAN;
        i32x4 A0 = __builtin_nontemporal_load(((const i32x4*)rp) + lane);        // ints 4l..4l+3
        i32x4 A1 = __builtin_nontemporal_load(((const i32x4*)rp) + 64 + lane);   // +256
        i32x4 A2 = __builtin_nontemporal_load(((const i32x4*)rp) + 128 + lane);  // +512
        int   T  = __builtin_nontemporal_load(rp + 768 + (lane & 31));           // tail 32

        unsigned wd[25];
        {
            u64 b0 = __ballot(A0.x != 0), b1 = __ballot(A0.y != 0);
            u64 b2 = __ballot(A0.z != 0), b3 = __ballot(A0.w != 0);
            wd[0] = (unsigned)b0; wd[1] = (unsigned)(b0 >> 32);
            wd[2] = (unsigned)b1; wd[3] = (unsigned)(b1 >> 32);
            wd[4] = (unsigned)b2; wd[5] = (unsigned)(b2 >> 32);
            wd[6] = (unsigned)b3; wd[7] = (unsigned)(b3 >> 32);
        }
        {
            u64 b0 = __ballot(A1.x != 0), b1 = __ballot(A1.y != 0);
            u64 b2 = __ballot(A1.z != 0), b3 = __ballot(A1.w != 0);
            wd[8]  = (unsigned)b0; wd[9]  = (unsigned)(b0 >> 32);
            wd[10] = (unsigned)b1; wd[11] = (unsigned)(b1 >> 32);
            wd[12] = (unsigned)b2; wd[13] = (unsigned)(b2 >> 32);
            wd[14] = (unsigned)b3; wd[15] = (unsigned)(b3 >> 32);
        }
        {
            u64 b0 = __ballot(A2.x != 0), b1 = __ballot(A2.y != 0);
            u64 b2 = __ballot(A2.z != 0), b3 = __ballot(A2.w != 0);
            wd[16] = (unsigned)b0; wd[17] = (unsigned)(b0 >> 32);
            wd[18] = (unsigned)b1; wd[19] = (unsigned)(b1 >> 32);
            wd[20] = (unsigned)b2; wd[21] = (unsigned)(b2 >> 32);
            wd[22] = (unsigned)b3; wd[23] = (unsigned)(b3 >> 32);
        }
        wd[24] = (unsigned)__ballot(T != 0);     // low 32 bits valid (lanes 32+ dup)

        if (lane == 0) {
            u32x4* dst = (u32x4*)&lm[r * LROW_STRIDE];
#pragma unroll
            for (int i = 0; i < 6; ++i) {
                u32x4 o = {wd[4 * i], wd[4 * i + 1], wd[4 * i + 2], wd[4 * i + 3]};
                dst[i] = o;
            }
            lm[r * LROW_STRIDE + 24] = wd[24];
        }
    }
    // No __syncthreads: masks are wave-private; compiler orders LDS w->r.

    // ---- Phase 2: expand (inverse permutation) + MFMA ----
    const short8* pB = (const short8*)Wswz + (size_t)kc * SPW * 4 * 64 + lane;
    const unsigned* mrow = lm + lrow * LROW_STRIDE;
    const int khi2 = khi * 2;

    f32x4 acc0 = {0.f, 0.f, 0.f, 0.f};
    f32x4 acc1 = acc0, acc2 = acc0, acc3 = acc0;

#pragma unroll
    for (int g = 0; g < 6; ++g) {                // steps s = 4g+u, u=0..3
        const int wb = (g >> 1) * 8 + (g & 1);   // word base {0,1,8,9,16,17}
        unsigned w0 = mrow[wb], w1 = mrow[wb + 2], w2 = mrow[wb + 4], w3 = mrow[wb + 6];
#pragma unroll
        for (int u = 0; u < 4; ++u) {
            short8 b0 = pB[0], b1 = pB[64], b2 = pB[128], b3 = pB[192];
            pB += 256;

            unsigned t0 = w0 >> (8 * u + khi2);
            unsigned t1 = w1 >> (8 * u + khi2);
            unsigned t2 = w2 >> (8 * u + khi2);
            unsigned t3 = w3 >> (8 * u + khi2);
            u32x4 av;
            av[0] = ((t0 & 1u) ? 0x3F80u : 0u) | ((t1 & 1u) ? 0x3F800000u : 0u);
            av[1] = ((t2 & 1u) ? 0x3F80u : 0u) | ((t3 & 1u) ? 0x3F800000u : 0u);
            av[2] = ((t0 & 2u) ? 0x3F80u : 0u) | ((t1 & 2u) ? 0x3F800000u : 0u);
            av[3] = ((t2 & 2u) ? 0x3F80u : 0u) | ((t3 & 2u) ? 0x3F800000u : 0u);
            short8 afrag = __builtin_bit_cast(short8, av);

            acc0 = __builtin_amdgcn_mfma_f32_16x16x32_bf16(afrag, b0, acc0, 0, 0, 0);
            acc1 = __builtin_amdgcn_mfma_f32_16x16x32_bf16(afrag, b1, acc1, 0, 0, 0);
            acc2 = __builtin_amdgcn_mfma_f32_16x16x32_bf16(afrag, b2, acc2, 0, 0, 0);
            acc3 = __builtin_amdgcn_mfma_f32_16x16x32_bf16(afrag, b3, acc3, 0, 0, 0);
        }
    }
    {   // step 24 tail: linear word, old (verified) byte path
        unsigned Mw = mrow[24];
        short8 b0 = pB[0], b1 = pB[64], b2 = pB[128], b3 = pB[192];
        unsigned mb = Mw >> (khi * 8);
        u32x4 av;
#pragma unroll
        for (int j = 0; j < 4; ++j)
            av[j] = (((mb >> (2 * j)) & 1u) ? 0x3F80u : 0u)
                  | (((mb >> (2 * j + 1)) & 1u) ? 0x3F800000u : 0u);
        short8 afrag = __builtin_bit_cast(short8, av);
        acc0 = __builtin_amdgcn_mfma_f32_16x16x32_bf16(afrag, b0, acc0, 0, 0, 0);
        acc1 = __builtin_amdgcn_mfma_f32_16x16x32_bf16(afrag, b1, acc1, 0, 0, 0);
        acc2 = __builtin_amdgcn_mfma_f32_16x16x32_bf16(afrag, b2, acc2, 0, 0, 0);
        acc3 = __builtin_amdgcn_mfma_f32_16x16x32_bf16(afrag, b3, acc3, 0, 0, 0);
    }

    // ---- Epilogue: atomic accumulate (D: col=lane&15, row=khi*4+i) ----
    float* obase = out + (size_t)mtile * 16 * EMBED;
#pragma unroll
    for (int i = 0; i < 4; ++i) {
        int orow = khi * 4 + i;
        atomicAdd(obase + (size_t)orow * EMBED +      lrow, acc0[i]);
        atomicAdd(obase + (size_t)orow * EMBED + 16 + lrow, acc1[i]);
        atomicAdd(obase + (size_t)orow * EMBED + 32 + lrow, acc2[i]);
        atomicAdd(obase + (size_t)orow * EMBED + 48 + lrow, acc3[i]);
    }
}

extern "C" void kernel_launch(void* const* d_in, const int* in_sizes, int n_in,
                              void* d_out, int out_size, void* d_ws, size_t ws_size,
                              hipStream_t stream) {
    const int*   idxm = (const int*)d_in[0];     // [4096][20000] int32
    const float* W    = (const float*)d_in[1];   // [20000][64] f32
    float*       out  = (float*)d_out;           // [4096][64] f32
    unsigned int* Wswz = (unsigned int*)d_ws;    // 2.56 MB swizzled bf16 W

    hipLaunchKernelGGL(prep_w_kernel, dim3(FIELD / 32), dim3(256), 0, stream,
                       W, Wswz, out);
    hipLaunchKernelGGL(emb_mfma_kernel, dim3(MTILES * KC / 4), dim3(256), 0, stream,
                       idxm, Wswz, out);
}